// Round 4
// baseline (360.977 us; speedup 1.0000x reference)
//
#include <hip/hip_runtime.h>
#include <hip/hip_bf16.h>
#include <math.h>

// EquivariantGraphConv fused kernel for MI355X (gfx950).
// B=2, N=512, D=HID=OUT=128.
//
// Round 2 -> 3 change: the round-2 bench showed VGPR_Count=64 with 115 MB of
// WRITE_SIZE (vs ~1.5 MB algorithmic) -> compiler capped registers and spilled
// the j-loop live set (~145 VGPRs) to scratch, making the kernel scratch-
// traffic-bound at 2 TB/s. Fix: __launch_bounds__(256, 3) -> ~170 VGPR cap,
// no spills, 3 blocks/CU (LDS 39.4KB allows 4; VGPR is the binding limit).
// Also: egnn_pre now uses 256 threads (A/B halves split across threads).
// (Round 4 = resubmission: round-3 bench failed on container acquisition.)

typedef float f32x4 __attribute__((ext_vector_type(4)));
typedef short short8 __attribute__((ext_vector_type(8)));

#define MFMA16(a, b, c) __builtin_amdgcn_mfma_f32_16x16x32_bf16((a), (b), (c), 0, 0, 0)

__device__ __forceinline__ short f2bf(float x) {
    union { float f; unsigned u; } v; v.f = x;
    unsigned r = v.u + 0x7FFFu + ((v.u >> 16) & 1u);  // RNE
    return (short)(r >> 16);
}

__device__ __forceinline__ float silu_f(float x) {
    return x * __builtin_amdgcn_rcpf(1.0f + __expf(-x));
}

// XOR swizzle for [rows][128] bf16 LDS tiles: permutes 16B chunks within each
// 128B row-window so that column-slice ds_read_b128 across rows is ~conflict-free
// (G4: row-major stride-256B is otherwise a 32-way conflict).
__device__ __forceinline__ int swz(int row, int col) {
    int byte = (row << 8) | (col << 1);
    byte ^= (row & 7) << 4;
    return byte >> 1;  // bf16-element index
}

// ---------- precompute: Abuf = feat @ eW1[0:128] + eb1 ; Bbuf = feat @ eW1[128:256]
// 256 threads: t<128 computes the A-half (col t), t>=128 the B-half (col t-128).
__global__ void egnn_pre(const float* __restrict__ feat, const float* __restrict__ eW1,
                         const float* __restrict__ eb1,
                         float* __restrict__ Abuf, float* __restrict__ Bbuf) {
    __shared__ float f[128];
    const int nid = blockIdx.x;  // b*512 + i
    const int t = threadIdx.x;   // 256 threads
    if (t < 128) f[t] = feat[nid * 128 + t];
    __syncthreads();
    const int col  = t & 127;
    const int half = t >> 7;                   // 0 -> A, 1 -> B
    const float* W = eW1 + (size_t)half * 128 * 128 + col;
    float acc = half ? 0.f : eb1[col];
    #pragma unroll 8
    for (int k = 0; k < 128; ++k) acc += f[k] * W[(size_t)k * 128];
    if (half == 0) Abuf[nid * 128 + col] = acc;
    else           Bbuf[nid * 128 + col] = acc;
}

// ---------- main fused kernel: one block per (b,i) node
__global__ void __launch_bounds__(256, 3) egnn_main(
    const float* __restrict__ features, const float* __restrict__ coords,
    const float* __restrict__ eW1, const float* __restrict__ eb2,
    const float* __restrict__ eW2,
    const float* __restrict__ nW1, const float* __restrict__ nb1,
    const float* __restrict__ nW2, const float* __restrict__ nb2,
    const float* __restrict__ cW1, const float* __restrict__ cb1,
    const float* __restrict__ cW2, const float* __restrict__ cb2,
    const float* __restrict__ Abuf, const float* __restrict__ Bbuf,
    float* __restrict__ out_feat, float* __restrict__ out_coord)
{
    constexpr int Nn = 512, TJ = 64;
    // se: union buffer. Prologue: stages W^T (128x128 bf16) for fragment loads.
    // Main loop: [0..8191] = s tile (64x128), [8192..16383] = edge_hidden tile.
    __shared__ __align__(16) short se[2 * 64 * 128];
    __shared__ float aw[128], wd[128], eb2s[128], cb1s[128], cw2s[128], fi[128];
    __shared__ float aggb[128], hbuf[128];
    __shared__ float dists[TJ], cdx[TJ], cdy[TJ], cdz[TJ];
    __shared__ float warr4[4][TJ];
    __shared__ float ci3[3];

    const int tid  = threadIdx.x;
    const int lane = tid & 63;
    const int wave = tid >> 6;
    const int node = blockIdx.x;       // == b*512 + i
    const int b    = node >> 9;

    // ---- stage per-node vectors
    if (tid < 128) {
        aw[tid]   = Abuf[node * 128 + tid];      // includes eb1
        wd[tid]   = eW1[256 * 128 + tid];        // distance row of eW1
        eb2s[tid] = eb2[tid];
        cb1s[tid] = cb1[tid];
        cw2s[tid] = cW2[tid];
        fi[tid]   = features[node * 128 + tid];
    }
    if (tid == 0) {
        ci3[0] = coords[node * 3 + 0];
        ci3[1] = coords[node * 3 + 1];
        ci3[2] = coords[node * 3 + 2];
    }

    // ---- stage eW2^T into se (bf16, swizzled), read register B-fragments, repeat for cW1
    short8 wf1[2][4], wf2[2][4];
    {
        const int n = tid & 127, k0 = (tid >> 7) * 64;
        for (int kc = 0; kc < 64; kc += 8) {
            short8 v;
            #pragma unroll
            for (int r = 0; r < 8; ++r) v[r] = f2bf(eW2[(k0 + kc + r) * 128 + n]);
            *(short8*)&se[swz(n, k0 + kc)] = v;
        }
    }
    __syncthreads();
    #pragma unroll
    for (int n2 = 0; n2 < 2; ++n2)
        #pragma unroll
        for (int k = 0; k < 4; ++k)
            wf1[n2][k] = *(const short8*)&se[swz(wave * 32 + n2 * 16 + (lane & 15),
                                                k * 32 + (lane >> 4) * 8)];
    __syncthreads();
    {
        const int n = tid & 127, k0 = (tid >> 7) * 64;
        for (int kc = 0; kc < 64; kc += 8) {
            short8 v;
            #pragma unroll
            for (int r = 0; r < 8; ++r) v[r] = f2bf(cW1[(k0 + kc + r) * 128 + n]);
            *(short8*)&se[swz(n, k0 + kc)] = v;
        }
    }
    __syncthreads();
    #pragma unroll
    for (int n2 = 0; n2 < 2; ++n2)
        #pragma unroll
        for (int k = 0; k < 4; ++k)
            wf2[n2][k] = *(const short8*)&se[swz(wave * 32 + n2 * 16 + (lane & 15),
                                                k * 32 + (lane >> 4) * 8)];
    __syncthreads();

    // per-lane column constants (C-fragment col = n2*16 + wave*32 + (lane&15))
    const int c0l = wave * 32 + (lane & 15);
    const float eb2_0 = eb2s[c0l], eb2_1 = eb2s[c0l + 16];
    const float cb1_0 = cb1s[c0l], cb1_1 = cb1s[c0l + 16];
    const float cw2_0 = cw2s[c0l], cw2_1 = cw2s[c0l + 16];
    const float cb2v  = cb2[0];
    const float cix = ci3[0], ciy = ci3[1], ciz = ci3[2];

    float sagg0 = 0.f, sagg1 = 0.f;          // per-col edge_hidden sums (pre-eb2)
    float cax = 0.f, cay = 0.f, caz = 0.f;   // coord accumulators (wave 0, tid<64)

    for (int j0 = 0; j0 < Nn; j0 += TJ) {
        // -- phase A: distances / coord diffs for this j-tile
        if (tid < TJ) {
            const int j = j0 + tid;
            float dx = cix - coords[(b * Nn + j) * 3 + 0];
            float dy = ciy - coords[(b * Nn + j) * 3 + 1];
            float dz = ciz - coords[(b * Nn + j) * 3 + 2];
            cdx[tid] = dx; cdy[tid] = dy; cdz[tid] = dz;
            dists[tid] = sqrtf(dx * dx + dy * dy + dz * dz + 1e-8f);
        }
        __syncthreads();

        // -- phase s: s = silu(Abuf_i + Bbuf_j + dist*wd) -> bf16 LDS tile
        {
            const int jr = tid >> 2, cb = (tid & 3) * 32;
            const float dj = dists[jr];
            const float* Bj = Bbuf + (size_t)(b * Nn + j0 + jr) * 128 + cb;
            #pragma unroll
            for (int cc = 0; cc < 32; cc += 8) {
                f32x4 x0 = *(const f32x4*)(Bj + cc);
                f32x4 x1 = *(const f32x4*)(Bj + cc + 4);
                short8 v;
                #pragma unroll
                for (int r = 0; r < 4; ++r) {
                    const int c = cb + cc + r;
                    v[r] = f2bf(silu_f(aw[c] + x0[r] + dj * wd[c]));
                }
                #pragma unroll
                for (int r = 0; r < 4; ++r) {
                    const int c = cb + cc + 4 + r;
                    v[4 + r] = f2bf(silu_f(aw[c] + x1[r] + dj * wd[c]));
                }
                *(short8*)&se[swz(jr, cb + cc)] = v;
            }
        }
        __syncthreads();

        // -- GEMM1: edge_hidden = s @ eW2 (per wave: 64 rows x 32-col strip)
        f32x4 acc1[4][2];
        #pragma unroll
        for (int m = 0; m < 4; ++m) { acc1[m][0] = (f32x4)(0.f); acc1[m][1] = (f32x4)(0.f); }
        #pragma unroll
        for (int m = 0; m < 4; ++m)
            #pragma unroll
            for (int k = 0; k < 4; ++k) {
                short8 a = *(const short8*)&se[swz(m * 16 + (lane & 15),
                                                  k * 32 + (lane >> 4) * 8)];
                acc1[m][0] = MFMA16(a, wf1[0][k], acc1[m][0]);
                acc1[m][1] = MFMA16(a, wf1[1][k], acc1[m][1]);
            }

        // -- write edge_hidden(+eb2) bf16 to LDS; accumulate j-sum for aggregation
        #pragma unroll
        for (int m = 0; m < 4; ++m)
            #pragma unroll
            for (int reg = 0; reg < 4; ++reg) {
                const int row = m * 16 + (lane >> 4) * 4 + reg;
                const float e0 = acc1[m][0][reg], e1 = acc1[m][1][reg];
                sagg0 += e0; sagg1 += e1;
                se[8192 + swz(row, c0l)]      = f2bf(e0 + eb2_0);
                se[8192 + swz(row, c0l + 16)] = f2bf(e1 + eb2_1);
            }
        __syncthreads();

        // -- GEMM2: c1 = edge_hidden @ cW1
        f32x4 acc2[4][2];
        #pragma unroll
        for (int m = 0; m < 4; ++m) { acc2[m][0] = (f32x4)(0.f); acc2[m][1] = (f32x4)(0.f); }
        #pragma unroll
        for (int m = 0; m < 4; ++m)
            #pragma unroll
            for (int k = 0; k < 4; ++k) {
                short8 a = *(const short8*)&se[8192 + swz(m * 16 + (lane & 15),
                                                          k * 32 + (lane >> 4) * 8)];
                acc2[m][0] = MFMA16(a, wf2[0][k], acc2[m][0]);
                acc2[m][1] = MFMA16(a, wf2[1][k], acc2[m][1]);
            }

        // -- coord weights: w[j] = silu(c1) . cW2 + cb2 ; butterfly over lane&15
        #pragma unroll
        for (int m = 0; m < 4; ++m)
            #pragma unroll
            for (int reg = 0; reg < 4; ++reg) {
                float v = silu_f(acc2[m][0][reg] + cb1_0) * cw2_0
                        + silu_f(acc2[m][1][reg] + cb1_1) * cw2_1;
                v += __shfl_xor(v, 1); v += __shfl_xor(v, 2);
                v += __shfl_xor(v, 4); v += __shfl_xor(v, 8);
                if ((lane & 15) == 0)
                    warr4[wave][m * 16 + (lane >> 4) * 4 + reg] = v;
            }
        __syncthreads();

        // -- coord accumulation (wave 0)
        if (tid < TJ) {
            const float w = warr4[0][tid] + warr4[1][tid] + warr4[2][tid] + warr4[3][tid] + cb2v;
            cax += w * cdx[tid]; cay += w * cdy[tid]; caz += w * cdz[tid];
        }
        __syncthreads();
    }

    // ---- aggregated = mean_j(edge_hidden) = sum/512 + eb2
    {
        float v0 = sagg0; v0 += __shfl_xor(v0, 16); v0 += __shfl_xor(v0, 32);
        float v1 = sagg1; v1 += __shfl_xor(v1, 16); v1 += __shfl_xor(v1, 32);
        if (lane < 16) {
            aggb[wave * 32 + lane]      = v0 * (1.f / 512.f) + eb2s[wave * 32 + lane];
            aggb[wave * 32 + 16 + lane] = v1 * (1.f / 512.f) + eb2s[wave * 32 + 16 + lane];
        }
    }
    // ---- coords out
    if (tid < 64) {
        float sx = cax, sy = cay, sz = caz;
        #pragma unroll
        for (int o = 1; o < 64; o <<= 1) {
            sx += __shfl_xor(sx, o); sy += __shfl_xor(sy, o); sz += __shfl_xor(sz, o);
        }
        if (tid == 0) {
            out_coord[node * 3 + 0] = cix + sx * (1.f / 512.f);
            out_coord[node * 3 + 1] = ciy + sy * (1.f / 512.f);
            out_coord[node * 3 + 2] = ciz + sz * (1.f / 512.f);
        }
    }
    __syncthreads();

    // ---- node MLP: out = silu([feat_i, agg] @ nW1 + nb1) @ nW2 + nb2  (scalar f32, tiny)
    if (tid < 128) {
        float acc = nb1[tid];
        #pragma unroll 4
        for (int k = 0; k < 128; ++k) acc += fi[k] * nW1[k * 128 + tid];
        #pragma unroll 4
        for (int k = 0; k < 128; ++k) acc += aggb[k] * nW1[(128 + k) * 128 + tid];
        hbuf[tid] = silu_f(acc);
    }
    __syncthreads();
    if (tid < 128) {
        float acc = nb2[tid];
        #pragma unroll 4
        for (int k = 0; k < 128; ++k) acc += hbuf[k] * nW2[k * 128 + tid];
        out_feat[node * 128 + tid] = acc;
    }
}

extern "C" void kernel_launch(void* const* d_in, const int* in_sizes, int n_in,
                              void* d_out, int out_size, void* d_ws, size_t ws_size,
                              hipStream_t stream)
{
    const float* features = (const float*)d_in[0];
    const float* coords   = (const float*)d_in[1];
    const float* eW1 = (const float*)d_in[2];
    const float* eb1 = (const float*)d_in[3];
    const float* eW2 = (const float*)d_in[4];
    const float* eb2 = (const float*)d_in[5];
    const float* nW1 = (const float*)d_in[6];
    const float* nb1 = (const float*)d_in[7];
    const float* nW2 = (const float*)d_in[8];
    const float* nb2 = (const float*)d_in[9];
    const float* cW1 = (const float*)d_in[10];
    const float* cb1 = (const float*)d_in[11];
    const float* cW2 = (const float*)d_in[12];
    const float* cb2 = (const float*)d_in[13];

    float* out = (float*)d_out;
    float* out_feat  = out;                       // (2,512,128)
    float* out_coord = out + 2 * 512 * 128;       // (2,512,3)

    float* Abuf = (float*)d_ws;                   // 2*512*128 f32
    float* Bbuf = Abuf + 2 * 512 * 128;           // 2*512*128 f32

    egnn_pre<<<1024, 256, 0, stream>>>(features, eW1, eb1, Abuf, Bbuf);
    egnn_main<<<1024, 256, 0, stream>>>(features, coords, eW1, eb2, eW2,
                                        nW1, nb1, nW2, nb2, cW1, cb1, cW2, cb2,
                                        Abuf, Bbuf, out_feat, out_coord);
}

// Round 5
// 231.200 us; speedup vs baseline: 1.5613x; 1.5613x over previous
//
#include <hip/hip_runtime.h>
#include <hip/hip_bf16.h>
#include <math.h>

// EquivariantGraphConv fused kernel for MI355X (gfx950).
// B=2, N=512, D=HID=OUT=128.
//
// Round 4 -> 5 restructure: rounds 2/4 showed the allocator spilling the
// j-loop live set (WRITE_SIZE 61-115 MB vs ~2 MB algorithmic) and the kernel
// latency-bound on spill-reload chains (MfmaUtil<6%, VALUBusy<22%, both idle).
// Key algebra: there is NO activation between the two edge GEMMs, so
//   c1 = (s@eW2+eb2)@cW1+cb1 = s@M + bias2,  M = eW2@cW1 (precomputed),
// and Sum_j edge_hidden = (Sum_j s)@eW2 + 512*eb2  (column sums of s).
// => ONE GEMM per edge tile, one weight-fragment set (32 VGPRs), no
// edge_hidden LDS round-trip, 2 barriers/iter (parity-buffered cd/warr).
// Peak live set ~110 VGPRs -> no spill pressure. launch_bounds(256,2).

typedef float f32x4 __attribute__((ext_vector_type(4)));
typedef short short8 __attribute__((ext_vector_type(8)));

#define MFMA16(a, b, c) __builtin_amdgcn_mfma_f32_16x16x32_bf16((a), (b), (c), 0, 0, 0)

__device__ __forceinline__ short f2bf(float x) {
    union { float f; unsigned u; } v; v.f = x;
    unsigned r = v.u + 0x7FFFu + ((v.u >> 16) & 1u);  // RNE
    return (short)(r >> 16);
}
__device__ __forceinline__ float bf2f(short s) {
    union { unsigned u; float f; } v; v.u = ((unsigned)(unsigned short)s) << 16;
    return v.f;
}
__device__ __forceinline__ float silu_f(float x) {
    return x * __builtin_amdgcn_rcpf(1.0f + __expf(-x));
}

// XOR swizzle for [rows][128] bf16 LDS tiles (G4: break stride-256B conflicts).
__device__ __forceinline__ int swz(int row, int col) {
    int byte = (row << 8) | (col << 1);
    byte ^= (row & 7) << 4;
    return byte >> 1;  // bf16-element index
}

// ---------- precompute: Abuf = feat @ eW1[0:128] + eb1 ; Bbuf = feat @ eW1[128:256]
__global__ void egnn_pre(const float* __restrict__ feat, const float* __restrict__ eW1,
                         const float* __restrict__ eb1,
                         float* __restrict__ Abuf, float* __restrict__ Bbuf) {
    __shared__ float f[128];
    const int nid = blockIdx.x;
    const int t = threadIdx.x;   // 256 threads
    if (t < 128) f[t] = feat[nid * 128 + t];
    __syncthreads();
    const int col  = t & 127;
    const int half = t >> 7;
    const float* W = eW1 + (size_t)half * 128 * 128 + col;
    float acc = half ? 0.f : eb1[col];
    #pragma unroll 8
    for (int k = 0; k < 128; ++k) acc += f[k] * W[(size_t)k * 128];
    if (half == 0) Abuf[nid * 128 + col] = acc;
    else           Bbuf[nid * 128 + col] = acc;
}

// ---------- precompute: M = eW2 @ cW1 (128x128), bias2 = eb2 @ cW1 + cb1 (128)
__global__ void egnn_wprep(const float* __restrict__ eW2, const float* __restrict__ cW1,
                           const float* __restrict__ eb2, const float* __restrict__ cb1,
                           float* __restrict__ Mws, float* __restrict__ bias2ws) {
    const int a = blockIdx.x;      // 0..128 (128 => bias2)
    const int c = threadIdx.x;     // 128 threads
    if (a < 128) {
        float acc = 0.f;
        #pragma unroll 8
        for (int h = 0; h < 128; ++h) acc += eW2[a * 128 + h] * cW1[h * 128 + c];
        Mws[a * 128 + c] = acc;
    } else {
        float acc = cb1[c];
        #pragma unroll 8
        for (int h = 0; h < 128; ++h) acc += eb2[h] * cW1[h * 128 + c];
        bias2ws[c] = acc;
    }
}

// ---------- main fused kernel: one block per (b,i) node
__global__ void __launch_bounds__(256, 2) egnn_main(
    const float* __restrict__ features, const float* __restrict__ coords,
    const float* __restrict__ eW1, const float* __restrict__ eW2,
    const float* __restrict__ eb2,
    const float* __restrict__ nW1, const float* __restrict__ nb1,
    const float* __restrict__ nW2, const float* __restrict__ nb2,
    const float* __restrict__ cW2, const float* __restrict__ cb2,
    const float* __restrict__ Abuf, const float* __restrict__ Bbuf,
    const float* __restrict__ Mws, const float* __restrict__ bias2ws,
    float* __restrict__ out_feat, float* __restrict__ out_coord)
{
    constexpr int Nn = 512;
    __shared__ __align__(16) short se[64 * 128];            // 16 KB s-tile
    __shared__ float aw[128], wd[128];
    __shared__ float cdp[2][3][64];                         // parity-buffered coord diffs
    __shared__ float warr[2][4][64];                        // parity-buffered w partials
    __shared__ float aggw[2][128], aggs[128], aggh[128], hbuf[128];
    __shared__ float cred[4][3];
    __shared__ float ci3[3];

    const int tid  = threadIdx.x;
    const int lane = tid & 63;
    const int wave = tid >> 6;
    const int node = blockIdx.x;       // b*512 + i
    const int b    = node >> 9;

    if (tid < 128) {
        aw[tid] = Abuf[node * 128 + tid];      // includes eb1
        wd[tid] = eW1[256 * 128 + tid];        // distance row of eW1
    }
    if (tid == 0) {
        ci3[0] = coords[node * 3 + 0];
        ci3[1] = coords[node * 3 + 1];
        ci3[2] = coords[node * 3 + 2];
    }

    // ---- M^T fragments straight from global (L2-resident, prologue-once)
    const int cfrag = wave * 32 + (lane & 15);
    const int koff  = (lane >> 4) * 8;
    short8 wfM[2][4];
    #pragma unroll
    for (int n2 = 0; n2 < 2; ++n2)
        #pragma unroll
        for (int k = 0; k < 4; ++k) {
            short8 v;
            #pragma unroll
            for (int j = 0; j < 8; ++j)
                v[j] = f2bf(Mws[(k * 32 + koff + j) * 128 + cfrag + n2 * 16]);
            wfM[n2][k] = v;
        }
    __syncthreads();

    const float b2_0  = bias2ws[cfrag], b2_1 = bias2ws[cfrag + 16];
    const float cw2_0 = cW2[cfrag],     cw2_1 = cW2[cfrag + 16];
    const float cb2v  = cb2[0];
    const float cix = ci3[0], ciy = ci3[1], ciz = ci3[2];

    const int jr = tid >> 2, cb = (tid & 3) * 32;   // build mapping
    const int acol = tid & 127, agrp = tid >> 7;    // agg re-read mapping

    float aggp = 0.f;                   // per-thread partial of Sum_j s[j][acol]
    float cax = 0.f, cay = 0.f, caz = 0.f;

    for (int t = 0; t < 8; ++t) {
        const int par = t & 1;
        // -- build: s = silu(aw + Bbuf_j + dist*wd) -> bf16 LDS (dist inline)
        {
            const int j = t * 64 + jr;
            const float dx = cix - coords[(b * Nn + j) * 3 + 0];
            const float dy = ciy - coords[(b * Nn + j) * 3 + 1];
            const float dz = ciz - coords[(b * Nn + j) * 3 + 2];
            const float dj = sqrtf(dx * dx + dy * dy + dz * dz + 1e-8f);
            if ((tid & 3) == 0) {
                cdp[par][0][jr] = dx; cdp[par][1][jr] = dy; cdp[par][2][jr] = dz;
            }
            const float* Bj = Bbuf + (size_t)(b * Nn + j) * 128 + cb;
            #pragma unroll
            for (int cc = 0; cc < 32; cc += 8) {
                f32x4 x0 = *(const f32x4*)(Bj + cc);
                f32x4 x1 = *(const f32x4*)(Bj + cc + 4);
                short8 v;
                #pragma unroll
                for (int r = 0; r < 4; ++r) {
                    const int c = cb + cc + r;
                    v[r] = f2bf(silu_f(aw[c] + x0[r] + dj * wd[c]));
                }
                #pragma unroll
                for (int r = 0; r < 4; ++r) {
                    const int c = cb + cc + 4 + r;
                    v[4 + r] = f2bf(silu_f(aw[c] + x1[r] + dj * wd[c]));
                }
                *(short8*)&se[swz(jr, cb + cc)] = v;
            }
        }
        __syncthreads();                                   // Bar1: tile ready

        // -- GEMM: c1 = s @ M + bias2 (acc init = bias2)
        f32x4 acc[4][2];
        #pragma unroll
        for (int m = 0; m < 4; ++m) {
            acc[m][0] = (f32x4){b2_0, b2_0, b2_0, b2_0};
            acc[m][1] = (f32x4){b2_1, b2_1, b2_1, b2_1};
        }
        #pragma unroll
        for (int m = 0; m < 4; ++m)
            #pragma unroll
            for (int k = 0; k < 4; ++k) {
                short8 a = *(const short8*)&se[swz(m * 16 + (lane & 15), k * 32 + koff)];
                acc[m][0] = MFMA16(a, wfM[0][k], acc[m][0]);
                acc[m][1] = MFMA16(a, wfM[1][k], acc[m][1]);
            }

        // -- agg partial: Sum over this tile's rows of s[., acol] (bf16 re-read)
        {
            float sacc = 0.f;
            #pragma unroll
            for (int r = 0; r < 32; ++r)
                sacc += bf2f(se[swz(agrp * 32 + r, acol)]);
            aggp += sacc;
        }

        // -- coord weights: w = silu(c1) . cW2 (this wave's 32-col slice)
        #pragma unroll
        for (int m = 0; m < 4; ++m)
            #pragma unroll
            for (int reg = 0; reg < 4; ++reg) {
                float v = silu_f(acc[m][0][reg]) * cw2_0
                        + silu_f(acc[m][1][reg]) * cw2_1;
                v += __shfl_xor(v, 1); v += __shfl_xor(v, 2);
                v += __shfl_xor(v, 4); v += __shfl_xor(v, 8);
                if ((lane & 15) == 0)
                    warr[par][wave][m * 16 + (lane >> 4) * 4 + reg] = v;
            }
        __syncthreads();                                   // Bar2: warr/cdp ready

        // -- coord accumulation: wave w handles rows w*16..w*16+15 (parity-safe)
        if (lane < 16) {
            const int row = wave * 16 + lane;
            const float w = warr[par][0][row] + warr[par][1][row]
                          + warr[par][2][row] + warr[par][3][row] + cb2v;
            cax += w * cdp[par][0][row];
            cay += w * cdp[par][1][row];
            caz += w * cdp[par][2][row];
        }
    }

    // ---- flush agg partials and coord sums
    aggw[agrp][acol] = aggp;
    {
        float sx = cax, sy = cay, sz = caz;
        sx += __shfl_xor(sx, 1); sy += __shfl_xor(sy, 1); sz += __shfl_xor(sz, 1);
        sx += __shfl_xor(sx, 2); sy += __shfl_xor(sy, 2); sz += __shfl_xor(sz, 2);
        sx += __shfl_xor(sx, 4); sy += __shfl_xor(sy, 4); sz += __shfl_xor(sz, 4);
        sx += __shfl_xor(sx, 8); sy += __shfl_xor(sy, 8); sz += __shfl_xor(sz, 8);
        if (lane == 0) { cred[wave][0] = sx; cred[wave][1] = sy; cred[wave][2] = sz; }
    }
    __syncthreads();
    if (tid < 128) aggs[tid] = aggw[0][tid] + aggw[1][tid];   // Sum_j s[j][tid]
    if (tid == 0) {
        const float sx = cred[0][0] + cred[1][0] + cred[2][0] + cred[3][0];
        const float sy = cred[0][1] + cred[1][1] + cred[2][1] + cred[3][1];
        const float sz = cred[0][2] + cred[1][2] + cred[2][2] + cred[3][2];
        out_coord[node * 3 + 0] = cix + sx * (1.f / 512.f);
        out_coord[node * 3 + 1] = ciy + sy * (1.f / 512.f);
        out_coord[node * 3 + 2] = ciz + sz * (1.f / 512.f);
    }
    __syncthreads();
    // ---- aggregated[c'] = (Sum_j s @ eW2)[c']/512 + eb2[c']
    if (tid < 128) {
        float acc = 0.f;
        #pragma unroll 4
        for (int c = 0; c < 128; ++c) acc += aggs[c] * eW2[c * 128 + tid];
        aggh[tid] = acc * (1.f / 512.f) + eb2[tid];
    }
    __syncthreads();
    // ---- node MLP
    if (tid < 128) {
        float acc = nb1[tid];
        #pragma unroll 4
        for (int k = 0; k < 128; ++k) acc += features[node * 128 + k] * nW1[k * 128 + tid];
        #pragma unroll 4
        for (int k = 0; k < 128; ++k) acc += aggh[k] * nW1[(128 + k) * 128 + tid];
        hbuf[tid] = silu_f(acc);
    }
    __syncthreads();
    if (tid < 128) {
        float acc = nb2[tid];
        #pragma unroll 4
        for (int k = 0; k < 128; ++k) acc += hbuf[k] * nW2[k * 128 + tid];
        out_feat[node * 128 + tid] = acc;
    }
}

extern "C" void kernel_launch(void* const* d_in, const int* in_sizes, int n_in,
                              void* d_out, int out_size, void* d_ws, size_t ws_size,
                              hipStream_t stream)
{
    const float* features = (const float*)d_in[0];
    const float* coords   = (const float*)d_in[1];
    const float* eW1 = (const float*)d_in[2];
    const float* eb1 = (const float*)d_in[3];
    const float* eW2 = (const float*)d_in[4];
    const float* eb2 = (const float*)d_in[5];
    const float* nW1 = (const float*)d_in[6];
    const float* nb1 = (const float*)d_in[7];
    const float* nW2 = (const float*)d_in[8];
    const float* nb2 = (const float*)d_in[9];
    const float* cW1 = (const float*)d_in[10];
    const float* cb1 = (const float*)d_in[11];
    const float* cW2 = (const float*)d_in[12];
    const float* cb2 = (const float*)d_in[13];

    float* out = (float*)d_out;
    float* out_feat  = out;                       // (2,512,128)
    float* out_coord = out + 2 * 512 * 128;       // (2,512,3)

    float* Abuf    = (float*)d_ws;                // 131072 f32
    float* Bbuf    = Abuf + 2 * 512 * 128;        // 131072 f32
    float* Mws     = Bbuf + 2 * 512 * 128;        // 16384 f32
    float* bias2ws = Mws + 128 * 128;             // 128 f32

    egnn_pre<<<1024, 256, 0, stream>>>(features, eW1, eb1, Abuf, Bbuf);
    egnn_wprep<<<129, 128, 0, stream>>>(eW2, cW1, eb2, cb1, Mws, bias2ws);
    egnn_main<<<1024, 256, 0, stream>>>(features, coords, eW1, eW2, eb2,
                                        nW1, nb1, nW2, nb2, cW2, cb2,
                                        Abuf, Bbuf, Mws, bias2ws,
                                        out_feat, out_coord);
}